// Round 5
// baseline (283.400 us; speedup 1.0000x reference)
//
#include <hip/hip_runtime.h>

// Problem constants (fixed by setup_inputs)
#define BQ   4
#define CQ   2
#define EQ   256
#define LQ   16000
#define WQ   40
#define STEP 20
#define TQ   ((LQ - 1) * STEP + WQ)   // 320020
#define TLF  255                      // owned-frame pitch per block (256 computed, 1 overlap)
#define OWN  (TLF * STEP)             // 5100 owned output samples per block
#define NBX  63                       // 63 * 5100 = 321300 >= 320020
#define SPAN (TLF * STEP + WQ)        // 5140 floats of LDS accumulation

// Pre-kernel: transpose basis [W][E] -> wsT [E][W] (fp32, rows contiguous)
// so the main loop reads each e-row with wave-uniform scalar loads (SGPRs).
__global__ void transpose_basis_kernel(const float* __restrict__ basis,
                                       float* __restrict__ wsT) {
    int i = blockIdx.x * 256 + threadIdx.x;
    if (i < EQ * WQ) {
        int e = i / WQ;
        int w = i - e * WQ;
        wsT[i] = basis[w * EQ + e];
    }
}

// One block: 256 threads = 256 frames, one channel (c = blockIdx.z).
// Thread ll computes frame f = 255*bx - 1 + ll over ALL 256 e:
//   frame[w] = sum_e mix[b,e,f] * mask[b,c,e,f] * wsT[e][w].
// Every wave sweeps the SAME e-sequence -> basis s_loads stay hot in the
// scalar cache (this was the R4 bottleneck: 4 concurrent e-ranges thrashed it).
// Overlap-add into LDS in 2 parity phases (disjoint ranges, no atomics), then
// one coalesced store of the disjoint span t in [5100*bx, 5100*bx+5100).
__global__ __launch_bounds__(256, 4) void decoder_kernel(
    const float* __restrict__ mix,    // [B,E,L]
    const float* __restrict__ mask,   // [B,C,E,L]
    const float* __restrict__ wsT,    // [E,W] transposed basis
    float* __restrict__ out)          // [B,C,T]
{
    __shared__ float outS[SPAN];      // 20.6 KB

    const int tid = threadIdx.x;
    const int ll  = tid;               // frame lane 0..255
    const int bx  = blockIdx.x;
    const int b   = blockIdx.y;
    const int c   = blockIdx.z;
    const int f   = TLF * bx - 1 + ll; // may be out of [0,LQ)

    // Clamp + validity multiplier keeps the e-loop branch-free (uniform CF
    // is required for the basis loads to select s_load).
    const int   fc    = min(max(f, 0), LQ - 1);
    const float valid = (f >= 0 && f < LQ) ? 1.0f : 0.0f;

    float acc[WQ];
#pragma unroll
    for (int w = 0; w < WQ; ++w) acc[w] = 0.0f;

    const float* mp = mix  + (size_t)b * EQ * LQ + fc;
    const float* kp = mask + ((size_t)(b * CQ + c)) * EQ * LQ + fc;

    for (int eo = 0; eo < EQ; eo += 4) {
        float m[4], k[4];
#pragma unroll
        for (int u = 0; u < 4; ++u) {
            m[u] = mp[(size_t)(eo + u) * LQ];
            k[u] = kp[(size_t)(eo + u) * LQ];
        }
#pragma unroll
        for (int u = 0; u < 4; ++u) {
            const float s  = m[u] * k[u] * valid;
            const float* bb = wsT + (eo + u) * WQ;   // wave-uniform -> s_load
#pragma unroll
            for (int w = 0; w < WQ; ++w) acc[w] = fmaf(s, bb[w], acc[w]);
        }
    }

    // Overlap-add into LDS. Even-ll ranges [20*ll, 20*ll+40) tile [0,5120)
    // exactly once -> plain store (acc==0 for invalid frames). Odd-ll then
    // accumulates; its tail [5120,5140) is written but never read back.
    const int base = ll * STEP;
    if ((ll & 1) == 0) {
#pragma unroll
        for (int w = 0; w < WQ; ++w) outS[base + w] = acc[w];
    }
    __syncthreads();
    if (ll & 1) {
#pragma unroll
        for (int w = 0; w < WQ; ++w) outS[base + w] += acc[w];
    }
    __syncthreads();

    // Store owned span: t = 5100*bx + i  <->  outS[20 + i], i in [0,5100)
    const size_t ob = ((size_t)b * CQ + c) * TQ + (size_t)OWN * bx;
    for (int i = tid; i < OWN; i += 256) {
        const long t = (long)OWN * bx + i;
        if (t < (long)TQ) {
            out[ob + i] = outS[STEP + i];
        }
    }
}

extern "C" void kernel_launch(void* const* d_in, const int* in_sizes, int n_in,
                              void* d_out, int out_size, void* d_ws, size_t ws_size,
                              hipStream_t stream) {
    const float* mix   = (const float*)d_in[0];
    const float* mask  = (const float*)d_in[1];
    const float* basis = (const float*)d_in[2];
    float* out = (float*)d_out;
    float* wsT = (float*)d_ws;   // needs EQ*WQ*4 = 40960 bytes

    transpose_basis_kernel<<<dim3((EQ * WQ + 255) / 256), 256, 0, stream>>>(basis, wsT);

    dim3 grid(NBX, BQ, CQ);
    decoder_kernel<<<grid, 256, 0, stream>>>(mix, mask, wsT, out);
}

// Round 6
// 251.855 us; speedup vs baseline: 1.1252x; 1.1252x over previous
//
#include <hip/hip_runtime.h>

// Problem constants (fixed by setup_inputs)
#define BQ   4
#define CQ   2
#define EQ   256
#define LQ   16000
#define WQ   40
#define STEP 20
#define TQ   ((LQ - 1) * STEP + WQ)   // 320020
#define TLF  255                      // owned-frame pitch per block (256 frames computed)
#define OWN  (TLF * STEP)             // 5100 owned output samples per block
#define NBX  63                       // 63 * 5100 = 321300 >= 320020
#define SPAN (TLF * STEP + WQ)        // 5140 floats per accumulation copy
#define NH   4                        // e-quarters (one per wave)
#define EH   (EQ / NH)                // 64 e's per wave
#define FPT  4                        // frames per thread (basis-fetch amortization)

// Pre-kernel: transpose basis [W][E] -> wsT [E][W] fp32 so the main kernel can
// stage it into LDS with coalesced, conflict-free copies.
__global__ void transpose_basis_kernel(const float* __restrict__ basis,
                                       float* __restrict__ wsT) {
    int i = blockIdx.x * 256 + threadIdx.x;
    if (i < EQ * WQ) {
        int e = i / WQ;
        int w = i - e * WQ;
        wsT[i] = basis[w * EQ + e];
    }
}

// One block: 256 threads = 4 waves. Wave wv owns e-quarter [wv*64, wv*64+64).
// Thread (wv, lane) computes FPT=4 frames idx = 64*j + lane (j=0..3),
// f = 255*bx - 1 + idx, accumulating acc[j][w] += mix*mask*basisT[e][w].
// One basis row (broadcast ds_read) feeds 160 FMAs -> the per-e delivery
// stall (the R2-R5 bottleneck) is amortized 4x.
// Epilogue: overlap-add into 2 LDS copies (wave-pair each), 4 serialized
// phases (wave-parity x lane-parity; within a phase all [20*idx,20*idx+40)
// ranges are disjoint) -> no atomics. LDS for basisT is reused (union).
__global__ __launch_bounds__(256, 2) void decoder_kernel(
    const float* __restrict__ mix,    // [B,E,L]
    const float* __restrict__ mask,   // [B,C,E,L]
    const float* __restrict__ wsT,    // [E,W] transposed basis
    float* __restrict__ out)          // [B,C,T]
{
    __shared__ __align__(16) float smem[2 * SPAN];  // 41.1 KB; basisT aliases [0,10240)

    const int tid  = threadIdx.x;
    const int lane = tid & 63;
    const int wv   = tid >> 6;        // e-quarter
    const int bx   = blockIdx.x;
    const int b    = blockIdx.y;
    const int c    = blockIdx.z;

    // Stage basisT = wsT into LDS (coalesced global, conflict-free LDS).
    float* basisT = smem;
    for (int i = tid; i < EQ * WQ; i += 256) basisT[i] = wsT[i];
    __syncthreads();

    // Frame indices and validity for the FPT frames of this thread.
    int   fc[FPT];
    float valid[FPT];
#pragma unroll
    for (int j = 0; j < FPT; ++j) {
        int f = TLF * bx - 1 + (j * 64 + lane);
        fc[j]    = min(max(f, 0), LQ - 1);
        valid[j] = (f >= 0 && f < LQ) ? 1.0f : 0.0f;
    }

    float4 acc[FPT][WQ / 4];
#pragma unroll
    for (int j = 0; j < FPT; ++j)
#pragma unroll
        for (int t = 0; t < WQ / 4; ++t) acc[j][t] = make_float4(0.f, 0.f, 0.f, 0.f);

    const size_t mb = ((size_t)b * EQ + wv * EH) * LQ;
    const size_t kb = (((size_t)(b * CQ + c)) * EQ + wv * EH) * LQ;

#pragma unroll 2
    for (int e = 0; e < EH; ++e) {
        float s[FPT];
#pragma unroll
        for (int j = 0; j < FPT; ++j) {
            float m = mix [mb + (size_t)e * LQ + fc[j]];
            float k = mask[kb + (size_t)e * LQ + fc[j]];
            s[j] = m * k * valid[j];
        }
        const float4* bt = (const float4*)&basisT[(wv * EH + e) * WQ];
#pragma unroll
        for (int t = 0; t < WQ / 4; ++t) {
            float4 bv = bt[t];   // wave-uniform broadcast read
#pragma unroll
            for (int j = 0; j < FPT; ++j) {
                acc[j][t].x = fmaf(s[j], bv.x, acc[j][t].x);
                acc[j][t].y = fmaf(s[j], bv.y, acc[j][t].y);
                acc[j][t].z = fmaf(s[j], bv.z, acc[j][t].z);
                acc[j][t].w = fmaf(s[j], bv.w, acc[j][t].w);
            }
        }
    }
    __syncthreads();   // basisT dead; smem becomes 2 accumulation copies

    // Overlap-add. Copy cp = wv>>1 accumulates waves {2cp, 2cp+1}.
    // Phase order: (wv&1==0, even lane) STORE; (0, odd) ADD; (1, even) ADD;
    // (1, odd) ADD. Even-idx ranges tile [0,5120) exactly; odd-idx ranges are
    // mutually disjoint. Tail [5120,5140) is written but never read back.
    float4* outC = (float4*)(smem + (wv >> 1) * SPAN);
    const int hp = wv & 1;
    const int lp = lane & 1;

    if (hp == 0 && lp == 0) {
#pragma unroll
        for (int j = 0; j < FPT; ++j) {
            float4* p = outC + (j * 64 + lane) * (STEP / 4) * 4 / 4;  // base = 20*idx floats
            p = (float4*)((float*)outC + (j * 64 + lane) * STEP);
#pragma unroll
            for (int t = 0; t < WQ / 4; ++t) p[t] = acc[j][t];
        }
    }
    __syncthreads();
    if (hp == 0 && lp == 1) {
#pragma unroll
        for (int j = 0; j < FPT; ++j) {
            float4* p = (float4*)((float*)outC + (j * 64 + lane) * STEP);
#pragma unroll
            for (int t = 0; t < WQ / 4; ++t) {
                float4 v = p[t];
                v.x += acc[j][t].x; v.y += acc[j][t].y;
                v.z += acc[j][t].z; v.w += acc[j][t].w;
                p[t] = v;
            }
        }
    }
    __syncthreads();
    if (hp == 1 && lp == 0) {
#pragma unroll
        for (int j = 0; j < FPT; ++j) {
            float4* p = (float4*)((float*)outC + (j * 64 + lane) * STEP);
#pragma unroll
            for (int t = 0; t < WQ / 4; ++t) {
                float4 v = p[t];
                v.x += acc[j][t].x; v.y += acc[j][t].y;
                v.z += acc[j][t].z; v.w += acc[j][t].w;
                p[t] = v;
            }
        }
    }
    __syncthreads();
    if (hp == 1 && lp == 1) {
#pragma unroll
        for (int j = 0; j < FPT; ++j) {
            float4* p = (float4*)((float*)outC + (j * 64 + lane) * STEP);
#pragma unroll
            for (int t = 0; t < WQ / 4; ++t) {
                float4 v = p[t];
                v.x += acc[j][t].x; v.y += acc[j][t].y;
                v.z += acc[j][t].z; v.w += acc[j][t].w;
                p[t] = v;
            }
        }
    }
    __syncthreads();

    // Store owned span: t = 5100*bx + i  <->  copy0[20+i] + copy1[20+i]
    const size_t ob = ((size_t)b * CQ + c) * TQ + (size_t)OWN * bx;
    for (int i = tid; i < OWN; i += 256) {
        const long t = (long)OWN * bx + i;
        if (t < (long)TQ) {
            out[ob + i] = smem[STEP + i] + smem[SPAN + STEP + i];
        }
    }
}

extern "C" void kernel_launch(void* const* d_in, const int* in_sizes, int n_in,
                              void* d_out, int out_size, void* d_ws, size_t ws_size,
                              hipStream_t stream) {
    const float* mix   = (const float*)d_in[0];
    const float* mask  = (const float*)d_in[1];
    const float* basis = (const float*)d_in[2];
    float* out = (float*)d_out;
    float* wsT = (float*)d_ws;   // needs EQ*WQ*4 = 40960 bytes

    transpose_basis_kernel<<<dim3((EQ * WQ + 255) / 256), 256, 0, stream>>>(basis, wsT);

    dim3 grid(NBX, BQ, CQ);
    decoder_kernel<<<grid, 256, 0, stream>>>(mix, mask, wsT, out);
}